// Round 2
// baseline (33353.259 us; speedup 1.0000x reference)
//
#include <hip/hip_runtime.h>
#include <math.h>

// ---------------- constants ----------------
static constexpr int B_   = 128;
static constexpr int ORG_ = 4;
static constexpr int L_   = 2048;
static constexpr int C1_  = 128;
static constexpr int C2_  = 64;
static constexpr int NG_  = 8;
static constexpr int VQD_ = 64;
static constexpr int VQN_ = 1024;

__device__ __forceinline__ float selu_f(float x) {
    const float scale = 1.0507009873554805f;
    const float alpha = 1.6732632423543772f;
    return scale * (x > 0.f ? x : alpha * expm1f(x));
}

// ---------------- generic direct conv1d ----------------
// out[b,o,t] = (sum_{i<cig} sum_{k<K} in[b, g*cig+i, t+k-P] * w[o*so + i*si + k*sk + koff]) * scale[o] + bias[o]
// g = o / cog.  Normal conv: so=CI*K si=K sk=1 koff=0 (cig=CI,cog=CO).
// Transposed conv (weight (CI,CO,K), flipped): so=K si=CO*K sk=-1 koff=K-1.
// Grouped: cig=CI/G, cog=CO/G, so=cig*K.
template<int K, int TW>
__global__ __launch_bounds__(256) void conv1d_kernel(
    const float* __restrict__ in, const float* __restrict__ w,
    const float* __restrict__ scale, const float* __restrict__ bias,
    float* __restrict__ out,
    int B, int CI, int CO, int T,
    int cig, int cog, int so, int si, int sk, int koff)
{
    constexpr int P  = (K - 1) / 2;
    constexpr int XW = TW + K - 1;
    const int ntile = T / TW;
    const long total = (long)B * CO * ntile;
    for (long idx = blockIdx.x * (long)blockDim.x + threadIdx.x; idx < total;
         idx += (long)gridDim.x * blockDim.x) {
        const int tile = (int)(idx % ntile);
        const int o    = (int)((idx / ntile) % CO);
        const int b    = (int)(idx / ((long)ntile * CO));
        const int t0   = tile * TW;
        const int g    = o / cog;
        const float* inb = in + ((long)b * CI + (long)g * cig) * T;
        const float* wo  = w + (long)o * so + koff;

        float acc[TW];
#pragma unroll
        for (int u = 0; u < TW; ++u) acc[u] = 0.f;

        for (int i = 0; i < cig; ++i) {
            const float* inc = inb + (long)i * T;
            float xin[XW];
#pragma unroll
            for (int j = 0; j < XW; ++j) {
                int tt = t0 + j - P;
                xin[j] = (tt >= 0 && tt < T) ? inc[tt] : 0.f;
            }
            const float* wi = wo + (long)i * si;
            float wk[K];
#pragma unroll
            for (int k = 0; k < K; ++k) wk[k] = wi[k * sk];
#pragma unroll
            for (int u = 0; u < TW; ++u) {
#pragma unroll
                for (int k = 0; k < K; ++k) acc[u] += xin[u + k] * wk[k];
            }
        }
        const float sc = scale ? scale[o] : 1.f;
        const float bi = bias  ? bias[o]  : 0.f;
        const long obase = ((long)b * CO + o) * T + t0;
#pragma unroll
        for (int u = 0; u < TW; ++u) out[obase + u] = acc[u] * sc + bi;
    }
}

// ---------------- GroupNorm stats: one block per (b,g) ----------------
__global__ __launch_bounds__(256) void gn_stats_kernel(
    const float* __restrict__ x, float* __restrict__ stats,
    int C, int T, int G)
{
    const int bg = blockIdx.x;          // b*G + g
    const int cpg = C / G;
    const int b = bg / G, g = bg % G;
    const float* base = x + ((long)b * C + (long)g * cpg) * T;
    const long n = (long)cpg * T;
    float s = 0.f, ss = 0.f;
    for (long i = threadIdx.x; i < n; i += blockDim.x) {
        float v = base[i];
        s += v; ss += v * v;
    }
#pragma unroll
    for (int off = 32; off; off >>= 1) {
        s  += __shfl_down(s, off);
        ss += __shfl_down(ss, off);
    }
    __shared__ float sh_s[4], sh_ss[4];
    const int wid = threadIdx.x >> 6, lane = threadIdx.x & 63;
    if (lane == 0) { sh_s[wid] = s; sh_ss[wid] = ss; }
    __syncthreads();
    if (threadIdx.x == 0) {
        float S = 0.f, SS = 0.f;
        for (int i = 0; i < 4; ++i) { S += sh_s[i]; SS += sh_ss[i]; }
        float inv_n = 1.f / (float)n;
        float mu  = S * inv_n;
        float var = SS * inv_n - mu * mu;
        stats[2 * bg]     = mu;
        stats[2 * bg + 1] = rsqrtf(var + 1e-5f);
    }
}

// ---------------- GroupNorm apply (+ optional residual, optional selu) ----------------
__global__ __launch_bounds__(256) void gn_apply_kernel(
    const float* __restrict__ x, const float* __restrict__ stats,
    const float* __restrict__ gamma, const float* __restrict__ beta,
    const float* __restrict__ res, float* __restrict__ out,
    long total, int C, int T, int G, int do_selu)
{
    const int cpg = C / G;
    for (long idx = blockIdx.x * (long)blockDim.x + threadIdx.x; idx < total;
         idx += (long)gridDim.x * blockDim.x) {
        const int c = (int)((idx / T) % C);
        const int b = (int)(idx / ((long)T * C));
        const int g = c / cpg;
        const float mu = stats[2 * (b * G + g)];
        const float rs = stats[2 * (b * G + g) + 1];
        float v = (x[idx] - mu) * rs * gamma[c] + beta[c];
        if (res) v += res[idx];
        if (do_selu) v = selu_f(v);
        out[idx] = v;
    }
}

// ---------------- MaxPool1d(2) ----------------
__global__ __launch_bounds__(256) void pool_kernel(
    const float* __restrict__ in, float* __restrict__ out, long total, int Tout)
{
    for (long idx = blockIdx.x * (long)blockDim.x + threadIdx.x; idx < total;
         idx += (long)gridDim.x * blockDim.x) {
        const int t = (int)(idx % Tout);
        const long bc = idx / Tout;
        const float a = in[bc * (2 * Tout) + 2 * t];
        const float b = in[bc * (2 * Tout) + 2 * t + 1];
        out[idx] = fmaxf(a, b);
    }
}

// ---------------- nearest Upsample(x2) ----------------
__global__ __launch_bounds__(256) void up_kernel(
    const float* __restrict__ in, float* __restrict__ out, long total, int Tout)
{
    for (long idx = blockIdx.x * (long)blockDim.x + threadIdx.x; idx < total;
         idx += (long)gridDim.x * blockDim.x) {
        const int t = (int)(idx % Tout);
        const long bc = idx / Tout;
        out[idx] = in[bc * (Tout / 2) + (t >> 1)];
    }
}

// ---------------- VQ: argmin over codes, write hq, accumulate loss ----------------
__global__ __launch_bounds__(256) void vq_kernel(
    const float* __restrict__ h, const float* __restrict__ codes,
    float* __restrict__ hq, float* __restrict__ loss,
    int B, int T, int NC)
{
    __shared__ float cs[64 * VQD_];
    const int n  = blockIdx.x * 256 + threadIdx.x;
    const int NP = B * T;
    const bool active = n < NP;
    const int b = n / T, t = n - b * T;

    float z[VQD_];
    if (active) {
#pragma unroll
        for (int c = 0; c < VQD_; ++c) z[c] = h[((long)b * VQD_ + c) * T + t];
    }

    float best = 3.4e38f;
    int bj = 0;
    for (int j0 = 0; j0 < NC; j0 += 64) {
        __syncthreads();
        for (int i = threadIdx.x; i < 64 * VQD_; i += 256)
            cs[i] = codes[(long)j0 * VQD_ + i];
        __syncthreads();
        if (active) {
            for (int j = 0; j < 64; ++j) {
                float d = 0.f;
#pragma unroll
                for (int c = 0; c < VQD_; ++c) {
                    float df = z[c] - cs[j * VQD_ + c];
                    d += df * df;
                }
                if (d < best) { best = d; bj = j0 + j; }
            }
        }
    }

    float l = 0.f;
    if (active) {
        const float* wj = codes + (long)bj * VQD_;
#pragma unroll
        for (int c = 0; c < VQD_; ++c) {
            float w = wj[c];
            hq[((long)b * VQD_ + c) * T + t] = w;
            float df = z[c] - w;
            l += df * df;
        }
    }
#pragma unroll
    for (int off = 32; off; off >>= 1) l += __shfl_down(l, off);
    if ((threadIdx.x & 63) == 0) atomicAdd(loss, l);
}

__global__ void zero_kernel(float* p) { p[0] = 0.f; }

__global__ void finalize_kernel(const float* __restrict__ loss, float* __restrict__ out,
                                float invNP, long off)
{
    float v = loss[0] * invNP;
    out[off]     = v;
    out[off + 1] = v;
}

// ---------------- host side ----------------
static inline int nblk(long total, int thr = 256, long cap = 262144) {
    long b = (total + thr - 1) / thr;
    if (b > cap) b = cap;
    if (b < 1) b = 1;
    return (int)b;
}

// run the full network for a batch chunk of Bc samples
static void run_chunk(const float* x, const float* const* W, float* out,
                      float* A, float* Bb, float* Cc, float* st, float* lossbuf,
                      int Bc, long nbuf, hipStream_t stream)
{
    const float* w0    = W[0];
    const float* g0_g  = W[1];
    const float* g0_b  = W[2];
    const float* wxa   = W[3];
    const float* gxa_g = W[4];
    const float* gxa_b = W[5];
    const float* wxb   = W[6];
    const float* gxb_g = W[7];
    const float* gxb_b = W[8];
    const float* wxc   = W[9];
    const float* gxc_g = W[10];
    const float* gxc_b = W[11];
    const float* w2    = W[12];
    const float* bn2_g = W[13];
    const float* bn2_b = W[14];
    const float* embed = W[15];
    const float* wd2   = W[16];
    const float* gd2_g = W[17];
    const float* gd2_b = W[18];
    const float* wd1a  = W[19];
    const float* gd1a_g= W[20];
    const float* gd1a_b= W[21];
    const float* wd1b  = W[22];
    const float* gd1b_g= W[23];
    const float* gd1b_b= W[24];
    const float* wd0   = W[25];
    const float* bd0   = W[26];

    const int THR = 256;

    // ===================== encoder =====================
    // conv0: (Bc,4,2048) -> (Bc,128,2048), K=7
    {
        long total = (long)Bc * C1_ * (L_ / 4);
        conv1d_kernel<7, 4><<<nblk(total), THR, 0, stream>>>(
            x, w0, nullptr, nullptr, A, Bc, ORG_, C1_, L_,
            ORG_, C1_, ORG_ * 7, 7, 1, 0);
        gn_stats_kernel<<<Bc * NG_, THR, 0, stream>>>(A, st, C1_, L_, NG_);
        long tt = (long)Bc * C1_ * L_;
        gn_apply_kernel<<<nblk(tt), THR, 0, stream>>>(A, st, g0_g, g0_b, nullptr, A,
                                                      tt, C1_, L_, NG_, 1);
    }

    const int D_ = C1_ / 2;  // 64

    int T = L_;
    for (int blk = 0; blk < 2; ++blk) {
        float* B0 = Bb;
        float* B1 = Bb + nbuf / 2;
        // y = selu(gn(conv1x1(h)))
        {
            long total = (long)Bc * D_ * (T / 4);
            conv1d_kernel<1, 4><<<nblk(total), THR, 0, stream>>>(
                A, wxa, nullptr, nullptr, B0, Bc, C1_, D_, T,
                C1_, D_, C1_, 1, 1, 0);
            gn_stats_kernel<<<Bc * NG_, THR, 0, stream>>>(B0, st, D_, T, NG_);
            long tt = (long)Bc * D_ * T;
            gn_apply_kernel<<<nblk(tt), THR, 0, stream>>>(B0, st, gxa_g, gxa_b, nullptr, B0,
                                                          tt, D_, T, NG_, 1);
        }
        // y = selu(gn(gconv5(y)))  groups=32, cig=cog=2
        {
            long total = (long)Bc * D_ * (T / 4);
            conv1d_kernel<5, 4><<<nblk(total), THR, 0, stream>>>(
                B0, wxb, nullptr, nullptr, B1, Bc, D_, D_, T,
                2, 2, 2 * 5, 5, 1, 0);
            gn_stats_kernel<<<Bc * NG_, THR, 0, stream>>>(B1, st, D_, T, NG_);
            long tt = (long)Bc * D_ * T;
            gn_apply_kernel<<<nblk(tt), THR, 0, stream>>>(B1, st, gxb_g, gxb_b, nullptr, B1,
                                                          tt, D_, T, NG_, 1);
        }
        // y = gn(conv1x1(y)); h = selu(h + y)
        {
            long total = (long)Bc * C1_ * (T / 4);
            conv1d_kernel<1, 4><<<nblk(total), THR, 0, stream>>>(
                B1, wxc, nullptr, nullptr, Cc, Bc, D_, C1_, T,
                D_, C1_, D_, 1, 1, 0);
            gn_stats_kernel<<<Bc * NG_, THR, 0, stream>>>(Cc, st, C1_, T, NG_);
            long tt = (long)Bc * C1_ * T;
            gn_apply_kernel<<<nblk(tt), THR, 0, stream>>>(Cc, st, gxc_g, gxc_b, A, Cc,
                                                          tt, C1_, T, NG_, 1);
        }
        // pool: T -> T/2, result back in A
        {
            int Tout = T / 2;
            long tt = (long)Bc * C1_ * Tout;
            pool_kernel<<<nblk(tt), THR, 0, stream>>>(Cc, A, tt, Tout);
            T = Tout;
        }
    }
    // T == 512, h in A (Bc,128,512)

    // res2: conv k3 128->64, then BN-eval affine
    {
        long total = (long)Bc * C2_ * (T / 4);
        conv1d_kernel<3, 4><<<nblk(total), THR, 0, stream>>>(
            A, w2, bn2_g, bn2_b, Cc, Bc, C1_, C2_, T,
            C1_, C2_, C1_ * 3, 3, 1, 0);
    }

    // ===================== VQ =====================
    {
        int NP = Bc * T;
        vq_kernel<<<(NP + 255) / 256, 256, 0, stream>>>(Cc, embed, A, lossbuf, Bc, T, VQN_);
    }

    // ===================== decoder =====================
    // deres2: h = selu(gn(tconv(hq, wd2)))   (64 -> 128, K=3)
    {
        long total = (long)Bc * C1_ * (T / 4);
        conv1d_kernel<3, 4><<<nblk(total), THR, 0, stream>>>(
            A, wd2, nullptr, nullptr, Bb, Bc, C2_, C1_, T,
            C2_, C1_, 3, C1_ * 3, -1, 2);
        gn_stats_kernel<<<Bc * NG_, THR, 0, stream>>>(Bb, st, C1_, T, NG_);
        long tt = (long)Bc * C1_ * T;
        gn_apply_kernel<<<nblk(tt), THR, 0, stream>>>(Bb, st, gd2_g, gd2_b, nullptr, Bb,
                                                      tt, C1_, T, NG_, 1);
    }

    // two (upsample + deres1) stages, shared weights
    float* hcur = Bb;   // (Bc,128,512)
    for (int blk = 0; blk < 2; ++blk) {
        int Tout = T * 2;
        float* U = (blk == 0) ? Cc : Bb;
        {
            long tt = (long)Bc * C1_ * Tout;
            up_kernel<<<nblk(tt), THR, 0, stream>>>(hcur, U, tt, Tout);
        }
        T = Tout;
        // y = selu(gn(tconv(U, wd1a)))  -> A
        {
            long total = (long)Bc * C1_ * (T / 4);
            conv1d_kernel<5, 4><<<nblk(total), THR, 0, stream>>>(
                U, wd1a, nullptr, nullptr, A, Bc, C1_, C1_, T,
                C1_, C1_, 5, C1_ * 5, -1, 4);
            gn_stats_kernel<<<Bc * NG_, THR, 0, stream>>>(A, st, C1_, T, NG_);
            long tt = (long)Bc * C1_ * T;
            gn_apply_kernel<<<nblk(tt), THR, 0, stream>>>(A, st, gd1a_g, gd1a_b, nullptr, A,
                                                          tt, C1_, T, NG_, 1);
        }
        // y = gn(tconv(y, wd1b)); h = selu(U + y) -> A
        {
            float* Y = (blk == 0) ? Bb : Cc;
            long total = (long)Bc * C1_ * (T / 4);
            conv1d_kernel<5, 4><<<nblk(total), THR, 0, stream>>>(
                A, wd1b, nullptr, nullptr, Y, Bc, C1_, C1_, T,
                C1_, C1_, 5, C1_ * 5, -1, 4);
            gn_stats_kernel<<<Bc * NG_, THR, 0, stream>>>(Y, st, C1_, T, NG_);
            long tt = (long)Bc * C1_ * T;
            gn_apply_kernel<<<nblk(tt), THR, 0, stream>>>(Y, st, gd1b_g, gd1b_b, U, A,
                                                          tt, C1_, T, NG_, 1);
        }
        hcur = A;
    }
    // T == 2048, h in A

    // deres0: recon = tconv(h, wd0) + bd0  (128 -> 4, K=7) straight into d_out
    {
        long total = (long)Bc * ORG_ * (T / 4);
        conv1d_kernel<7, 4><<<nblk(total), THR, 0, stream>>>(
            A, wd0, nullptr, bd0, out, Bc, C1_, ORG_, T,
            C1_, ORG_, 7, ORG_ * 7, -1, 6);
    }
}

extern "C" void kernel_launch(void* const* d_in, const int* in_sizes, int n_in,
                              void* d_out, int out_size, void* d_ws, size_t ws_size,
                              hipStream_t stream) {
    const float* x = (const float*)d_in[0];
    const float* W[27];
    for (int i = 0; i < 27; ++i) W[i] = (const float*)d_in[i + 1];

    float* out = (float*)d_out;

    // Choose the largest batch chunk whose 3 ping-pong buffers fit in d_ws.
    // need(Bc) = (3 * Bc*C1*L + stats(4096) + loss(64)) * 4 bytes
    int Bc = 0;
    for (int cand = B_; cand >= 1; cand >>= 1) {
        size_t need = ((size_t)3 * cand * C1_ * L_ + 4096 + 64) * sizeof(float);
        if (need <= ws_size) { Bc = cand; break; }
    }
    if (Bc == 0) return;  // cannot run at all

    const long nbuf = (long)Bc * C1_ * L_;
    float* A  = (float*)d_ws;
    float* Bb = A + nbuf;
    float* Cc = Bb + nbuf;
    float* st = Cc + nbuf;
    float* lossbuf = st + 4096;

    zero_kernel<<<1, 1, 0, stream>>>(lossbuf);

    for (int b0 = 0; b0 < B_; b0 += Bc) {
        const float* xc = x + (long)b0 * ORG_ * L_;
        float* outc = out + (long)b0 * ORG_ * L_;
        run_chunk(xc, W, outc, A, Bb, Cc, st, lossbuf, Bc, nbuf, stream);
    }

    // losses: commit_loss == vq_loss numerically (stop_gradient doesn't change values)
    {
        float invNP = 1.f / (float)(B_ * (L_ / 4));  // N = 128*512 = 65536
        finalize_kernel<<<1, 1, 0, stream>>>(lossbuf, out, invNP, (long)out_size - 2);
    }
}

// Round 3
// 5535.720 us; speedup vs baseline: 6.0251x; 6.0251x over previous
//
#include <hip/hip_runtime.h>
#include <math.h>

// ---------------- constants ----------------
static constexpr int B_   = 128;
static constexpr int ORG_ = 4;
static constexpr int L_   = 2048;
static constexpr int C1_  = 128;
static constexpr int C2_  = 64;
static constexpr int NG_  = 8;
static constexpr int VQD_ = 64;
static constexpr int VQN_ = 1024;
static constexpr int TT_  = 64;   // time-tile
static constexpr int RS_  = 72;   // LDS row stride (floats, 16B-aligned, fits TT+6)

__device__ __forceinline__ float selu_f(float x) {
    const float scale = 1.0507009873554805f;
    const float alpha = 1.6732632423543772f;
    return scale * (x > 0.f ? x : alpha * expm1f(x));
}

// ---------------- weight prep: wT[(i*K + k)*CO + o] = w[o*so + i*si + k*sk + koff]
// Handles normal conv, transposed conv (flip via sk=-1,koff=K-1), grouped (cig range).
__global__ void wprep_kernel(const float* __restrict__ w, float* __restrict__ wT,
                             int CO, int cig, int K, int so, int si, int sk, int koff)
{
    int idx = blockIdx.x * 256 + threadIdx.x;
    int total = cig * K * CO;
    if (idx >= total) return;
    int o = idx % CO;
    int r = idx / CO;       // r = i*K + k
    int i = r / K, k = r % K;
    wT[idx] = w[(long)o * so + (long)i * si + (long)k * sk + koff];
}

// ---------------- LDS-tiled conv: one block = (b, 64-wide t tile), all CO channels
// thread: o = tid % CO, slot = tid / CO, computes NT = CO*TT/256 consecutive t.
// Input tile staged in LDS (zero-padded at sequence edges). Weights from wT (coalesced in o).
template<int K, int CO>
__global__ __launch_bounds__(256) void conv_tile_kernel(
    const float* __restrict__ in, const float* __restrict__ wT,
    const float* __restrict__ scale, const float* __restrict__ bias,
    float* __restrict__ out,
    int CI, int T, int cig, int cog)
{
    constexpr int P  = (K - 1) / 2;
    constexpr int NT = (CO * TT_) / 256;
    constexpr int XW = NT + K - 1;
    extern __shared__ float lds[];

    const int tile = blockIdx.x;
    const int b    = blockIdx.y;
    const int t0g  = tile * TT_;
    const int span = TT_ + 2 * P;
    const float* inb = in + (long)b * CI * T;

    // stage padded input tile
    for (int idx = threadIdx.x; idx < CI * span; idx += 256) {
        int i = idx / span, j = idx % span;
        int tt = t0g + j - P;
        lds[i * RS_ + j] = (tt >= 0 && tt < T) ? inb[(long)i * T + tt] : 0.f;
    }
    __syncthreads();

    const int o    = threadIdx.x % CO;
    const int slot = threadIdx.x / CO;
    const int t0   = slot * NT;
    const int g    = o / cog;
    const float* wrow = wT + o;

    float acc[NT];
#pragma unroll
    for (int u = 0; u < NT; ++u) acc[u] = 0.f;

    for (int i = 0; i < cig; ++i) {
        const int irow = g * cig + i;
        float xin[(XW + 3) & ~3];
        if constexpr (NT % 4 == 0) {
            // t0 is a multiple of 4 -> 16B-aligned float4 loads from LDS
            constexpr int X4 = (XW + 3) / 4;
            const float4* l4 = reinterpret_cast<const float4*>(&lds[irow * RS_ + t0]);
#pragma unroll
            for (int j = 0; j < X4; ++j) {
                float4 v = l4[j];
                xin[4 * j]     = v.x;
                xin[4 * j + 1] = v.y;
                xin[4 * j + 2] = v.z;
                xin[4 * j + 3] = v.w;
            }
        } else {
#pragma unroll
            for (int j = 0; j < XW; ++j) xin[j] = lds[irow * RS_ + t0 + j];
        }
        float wk[K];
#pragma unroll
        for (int k = 0; k < K; ++k) wk[k] = wrow[(i * K + k) * CO];
#pragma unroll
        for (int u = 0; u < NT; ++u) {
#pragma unroll
            for (int k = 0; k < K; ++k) acc[u] = fmaf(xin[u + k], wk[k], acc[u]);
        }
    }

    const float sc = scale ? scale[o] : 1.f;
    const float bi = bias  ? bias[o]  : 0.f;
    float* ob = out + ((long)b * CO + o) * T + t0g + t0;
#pragma unroll
    for (int u = 0; u < NT; ++u) ob[u] = acc[u] * sc + bi;
}

// ---------------- GroupNorm stats: one block per (b,g) ----------------
__global__ __launch_bounds__(256) void gn_stats_kernel(
    const float* __restrict__ x, float* __restrict__ stats,
    int C, int T, int G)
{
    const int bg = blockIdx.x;
    const int cpg = C / G;
    const int b = bg / G, g = bg % G;
    const float* base = x + ((long)b * C + (long)g * cpg) * T;
    const long n = (long)cpg * T;
    float s = 0.f, ss = 0.f;
    for (long i = threadIdx.x; i < n; i += blockDim.x) {
        float v = base[i];
        s += v; ss += v * v;
    }
#pragma unroll
    for (int off = 32; off; off >>= 1) {
        s  += __shfl_down(s, off);
        ss += __shfl_down(ss, off);
    }
    __shared__ float sh_s[4], sh_ss[4];
    const int wid = threadIdx.x >> 6, lane = threadIdx.x & 63;
    if (lane == 0) { sh_s[wid] = s; sh_ss[wid] = ss; }
    __syncthreads();
    if (threadIdx.x == 0) {
        float S = 0.f, SS = 0.f;
        for (int i = 0; i < 4; ++i) { S += sh_s[i]; SS += sh_ss[i]; }
        float inv_n = 1.f / (float)n;
        float mu  = S * inv_n;
        float var = SS * inv_n - mu * mu;
        stats[2 * bg]     = mu;
        stats[2 * bg + 1] = rsqrtf(var + 1e-5f);
    }
}

// ---------------- GroupNorm apply (+ optional residual, optional selu) ----------------
__global__ __launch_bounds__(256) void gn_apply_kernel(
    const float* __restrict__ x, const float* __restrict__ stats,
    const float* __restrict__ gamma, const float* __restrict__ beta,
    const float* __restrict__ res, float* __restrict__ out,
    long total, int C, int T, int G, int do_selu)
{
    const int cpg = C / G;
    for (long idx = blockIdx.x * (long)blockDim.x + threadIdx.x; idx < total;
         idx += (long)gridDim.x * blockDim.x) {
        const int c = (int)((idx / T) % C);
        const int b = (int)(idx / ((long)T * C));
        const int g = c / cpg;
        const float mu = stats[2 * (b * G + g)];
        const float rs = stats[2 * (b * G + g) + 1];
        float v = (x[idx] - mu) * rs * gamma[c] + beta[c];
        if (res) v += res[idx];
        if (do_selu) v = selu_f(v);
        out[idx] = v;
    }
}

// ---------------- MaxPool1d(2) ----------------
__global__ __launch_bounds__(256) void pool_kernel(
    const float* __restrict__ in, float* __restrict__ out, long total, int Tout)
{
    for (long idx = blockIdx.x * (long)blockDim.x + threadIdx.x; idx < total;
         idx += (long)gridDim.x * blockDim.x) {
        const int t = (int)(idx % Tout);
        const long bc = idx / Tout;
        const float a = in[bc * (2 * Tout) + 2 * t];
        const float b = in[bc * (2 * Tout) + 2 * t + 1];
        out[idx] = fmaxf(a, b);
    }
}

// ---------------- nearest Upsample(x2) ----------------
__global__ __launch_bounds__(256) void up_kernel(
    const float* __restrict__ in, float* __restrict__ out, long total, int Tout)
{
    for (long idx = blockIdx.x * (long)blockDim.x + threadIdx.x; idx < total;
         idx += (long)gridDim.x * blockDim.x) {
        const int t = (int)(idx % Tout);
        const long bc = idx / Tout;
        out[idx] = in[bc * (Tout / 2) + (t >> 1)];
    }
}

// ---------------- VQ: argmin over codes, write hq, accumulate loss ----------------
__global__ __launch_bounds__(256) void vq_kernel(
    const float* __restrict__ h, const float* __restrict__ codes,
    float* __restrict__ hq, float* __restrict__ loss,
    int B, int T, int NC)
{
    __shared__ float cs[64 * VQD_];
    const int n  = blockIdx.x * 256 + threadIdx.x;
    const int NP = B * T;
    const bool active = n < NP;
    const int b = n / T, t = n - b * T;

    float z[VQD_];
    if (active) {
#pragma unroll
        for (int c = 0; c < VQD_; ++c) z[c] = h[((long)b * VQD_ + c) * T + t];
    }

    float best = 3.4e38f;
    int bj = 0;
    for (int j0 = 0; j0 < NC; j0 += 64) {
        __syncthreads();
        for (int i = threadIdx.x; i < 64 * VQD_; i += 256)
            cs[i] = codes[(long)j0 * VQD_ + i];
        __syncthreads();
        if (active) {
            for (int j = 0; j < 64; ++j) {
                float d = 0.f;
#pragma unroll
                for (int c = 0; c < VQD_; ++c) {
                    float df = z[c] - cs[j * VQD_ + c];
                    d += df * df;
                }
                if (d < best) { best = d; bj = j0 + j; }
            }
        }
    }

    float l = 0.f;
    if (active) {
        const float* wj = codes + (long)bj * VQD_;
#pragma unroll
        for (int c = 0; c < VQD_; ++c) {
            float w = wj[c];
            hq[((long)b * VQD_ + c) * T + t] = w;
            float df = z[c] - w;
            l += df * df;
        }
    }
#pragma unroll
    for (int off = 32; off; off >>= 1) l += __shfl_down(l, off);
    if ((threadIdx.x & 63) == 0) atomicAdd(loss, l);
}

__global__ void zero_kernel(float* p) { p[0] = 0.f; }

__global__ void finalize_kernel(const float* __restrict__ loss, float* __restrict__ out,
                                float invNP, long off)
{
    float v = loss[0] * invNP;
    out[off]     = v;
    out[off + 1] = v;
}

// ---------------- host side ----------------
static inline int nblk(long total, int thr = 256, long cap = 262144) {
    long b = (total + thr - 1) / thr;
    if (b > cap) b = cap;
    if (b < 1) b = 1;
    return (int)b;
}

struct WT {  // offsets (floats) into the wT pool
    long w0, wxa, wxb, wxc, w2, wd2, wd1a, wd1b, wd0, total;
};
static WT wt_offsets() {
    WT o; long p = 0;
    o.w0   = p; p += (long)ORG_ * 7 * C1_;        // 3584
    o.wxa  = p; p += (long)C1_ * 1 * (C1_ / 2);   // 8192
    o.wxb  = p; p += 2L * 5 * (C1_ / 2);          // 640
    o.wxc  = p; p += (long)(C1_ / 2) * 1 * C1_;   // 8192
    o.w2   = p; p += (long)C1_ * 3 * C2_;         // 24576
    o.wd2  = p; p += (long)C2_ * 3 * C1_;         // 24576
    o.wd1a = p; p += (long)C1_ * 5 * C1_;         // 81920
    o.wd1b = p; p += (long)C1_ * 5 * C1_;         // 81920
    o.wd0  = p; p += (long)C1_ * 7 * ORG_;        // 3584
    o.total = p;                                  // 237184
    return o;
}

static void run_chunk(const float* x, const float* const* W, const float* wt,
                      const WT& wo, float* out,
                      float* A, float* Bb, float* Cc, float* st, float* lossbuf,
                      int Bc, long nbuf, hipStream_t stream)
{
    const float* g0_g  = W[1];
    const float* g0_b  = W[2];
    const float* gxa_g = W[4];
    const float* gxa_b = W[5];
    const float* gxb_g = W[7];
    const float* gxb_b = W[8];
    const float* gxc_g = W[10];
    const float* gxc_b = W[11];
    const float* bn2_g = W[13];
    const float* bn2_b = W[14];
    const float* embed = W[15];
    const float* gd2_g = W[17];
    const float* gd2_b = W[18];
    const float* gd1a_g= W[20];
    const float* gd1a_b= W[21];
    const float* gd1b_g= W[23];
    const float* gd1b_b= W[24];
    const float* bd0   = W[26];

    const int THR = 256;
    const int D_ = C1_ / 2;  // 64

    // ===================== encoder =====================
    // conv0: (Bc,4,2048) -> (Bc,128,2048), K=7
    {
        conv_tile_kernel<7, 128><<<dim3(L_ / TT_, Bc), THR, ORG_ * RS_ * 4, stream>>>(
            x, wt + wo.w0, nullptr, nullptr, A, ORG_, L_, ORG_, C1_);
        gn_stats_kernel<<<Bc * NG_, THR, 0, stream>>>(A, st, C1_, L_, NG_);
        long tt = (long)Bc * C1_ * L_;
        gn_apply_kernel<<<nblk(tt), THR, 0, stream>>>(A, st, g0_g, g0_b, nullptr, A,
                                                      tt, C1_, L_, NG_, 1);
    }

    int T = L_;
    for (int blk = 0; blk < 2; ++blk) {
        float* B0 = Bb;
        float* B1 = Bb + nbuf / 2;
        // y = selu(gn(conv1x1(h)))
        {
            conv_tile_kernel<1, 64><<<dim3(T / TT_, Bc), THR, C1_ * RS_ * 4, stream>>>(
                A, wt + wo.wxa, nullptr, nullptr, B0, C1_, T, C1_, D_);
            gn_stats_kernel<<<Bc * NG_, THR, 0, stream>>>(B0, st, D_, T, NG_);
            long tt = (long)Bc * D_ * T;
            gn_apply_kernel<<<nblk(tt), THR, 0, stream>>>(B0, st, gxa_g, gxa_b, nullptr, B0,
                                                          tt, D_, T, NG_, 1);
        }
        // y = selu(gn(gconv5(y)))  groups=32, cig=cog=2
        {
            conv_tile_kernel<5, 64><<<dim3(T / TT_, Bc), THR, D_ * RS_ * 4, stream>>>(
                B0, wt + wo.wxb, nullptr, nullptr, B1, D_, T, 2, 2);
            gn_stats_kernel<<<Bc * NG_, THR, 0, stream>>>(B1, st, D_, T, NG_);
            long tt = (long)Bc * D_ * T;
            gn_apply_kernel<<<nblk(tt), THR, 0, stream>>>(B1, st, gxb_g, gxb_b, nullptr, B1,
                                                          tt, D_, T, NG_, 1);
        }
        // y = gn(conv1x1(y)); h = selu(h + y)
        {
            conv_tile_kernel<1, 128><<<dim3(T / TT_, Bc), THR, D_ * RS_ * 4, stream>>>(
                B1, wt + wo.wxc, nullptr, nullptr, Cc, D_, T, D_, C1_);
            gn_stats_kernel<<<Bc * NG_, THR, 0, stream>>>(Cc, st, C1_, T, NG_);
            long tt = (long)Bc * C1_ * T;
            gn_apply_kernel<<<nblk(tt), THR, 0, stream>>>(Cc, st, gxc_g, gxc_b, A, Cc,
                                                          tt, C1_, T, NG_, 1);
        }
        // pool: T -> T/2, result back in A
        {
            int Tout = T / 2;
            long tt = (long)Bc * C1_ * Tout;
            pool_kernel<<<nblk(tt), THR, 0, stream>>>(Cc, A, tt, Tout);
            T = Tout;
        }
    }
    // T == 512, h in A (Bc,128,512)

    // res2: conv k3 128->64, BN-eval affine in epilogue
    {
        conv_tile_kernel<3, 64><<<dim3(T / TT_, Bc), THR, C1_ * RS_ * 4, stream>>>(
            A, wt + wo.w2, bn2_g, bn2_b, Cc, C1_, T, C1_, C2_);
    }

    // ===================== VQ =====================
    {
        int NP = Bc * T;
        vq_kernel<<<(NP + 255) / 256, 256, 0, stream>>>(Cc, embed, A, lossbuf, Bc, T, VQN_);
    }

    // ===================== decoder =====================
    // deres2: h = selu(gn(tconv(hq, wd2)))   (64 -> 128, K=3)
    {
        conv_tile_kernel<3, 128><<<dim3(T / TT_, Bc), THR, C2_ * RS_ * 4, stream>>>(
            A, wt + wo.wd2, nullptr, nullptr, Bb, C2_, T, C2_, C1_);
        gn_stats_kernel<<<Bc * NG_, THR, 0, stream>>>(Bb, st, C1_, T, NG_);
        long tt = (long)Bc * C1_ * T;
        gn_apply_kernel<<<nblk(tt), THR, 0, stream>>>(Bb, st, gd2_g, gd2_b, nullptr, Bb,
                                                      tt, C1_, T, NG_, 1);
    }

    // two (upsample + deres1) stages, shared weights
    float* hcur = Bb;   // (Bc,128,512)
    for (int blk = 0; blk < 2; ++blk) {
        int Tout = T * 2;
        float* U = (blk == 0) ? Cc : Bb;
        {
            long tt = (long)Bc * C1_ * Tout;
            up_kernel<<<nblk(tt), THR, 0, stream>>>(hcur, U, tt, Tout);
        }
        T = Tout;
        // y = selu(gn(tconv(U, wd1a)))  -> A
        {
            conv_tile_kernel<5, 128><<<dim3(T / TT_, Bc), THR, C1_ * RS_ * 4, stream>>>(
                U, wt + wo.wd1a, nullptr, nullptr, A, C1_, T, C1_, C1_);
            gn_stats_kernel<<<Bc * NG_, THR, 0, stream>>>(A, st, C1_, T, NG_);
            long tt = (long)Bc * C1_ * T;
            gn_apply_kernel<<<nblk(tt), THR, 0, stream>>>(A, st, gd1a_g, gd1a_b, nullptr, A,
                                                          tt, C1_, T, NG_, 1);
        }
        // y = gn(tconv(y, wd1b)); h = selu(U + y) -> A
        {
            float* Y = (blk == 0) ? Bb : Cc;
            conv_tile_kernel<5, 128><<<dim3(T / TT_, Bc), THR, C1_ * RS_ * 4, stream>>>(
                A, wt + wo.wd1b, nullptr, nullptr, Y, C1_, T, C1_, C1_);
            gn_stats_kernel<<<Bc * NG_, THR, 0, stream>>>(Y, st, C1_, T, NG_);
            long tt = (long)Bc * C1_ * T;
            gn_apply_kernel<<<nblk(tt), THR, 0, stream>>>(Y, st, gd1b_g, gd1b_b, U, A,
                                                          tt, C1_, T, NG_, 1);
        }
        hcur = A;
    }
    // T == 2048, h in A

    // deres0: recon = tconv(h, wd0) + bd0  (128 -> 4, K=7) into d_out
    {
        conv_tile_kernel<7, 4><<<dim3(T / TT_, Bc), THR, C1_ * RS_ * 4, stream>>>(
            A, wt + wo.wd0, nullptr, bd0, out, C1_, T, C1_, ORG_);
    }
}

extern "C" void kernel_launch(void* const* d_in, const int* in_sizes, int n_in,
                              void* d_out, int out_size, void* d_ws, size_t ws_size,
                              hipStream_t stream) {
    const float* x = (const float*)d_in[0];
    const float* W[27];
    for (int i = 0; i < 27; ++i) W[i] = (const float*)d_in[i + 1];

    float* out = (float*)d_out;
    const WT wo = wt_offsets();

    // workspace: [wT pool | stats | loss | A | B | C]
    const long FIXED = 262144 + 4096 + 64;   // floats
    int Bc = 0;
    for (int cand = B_; cand >= 1; cand >>= 1) {
        size_t need = ((size_t)FIXED + (size_t)3 * cand * C1_ * L_) * sizeof(float);
        if (need <= ws_size) { Bc = cand; break; }
    }
    if (Bc == 0) return;

    float* wt      = (float*)d_ws;
    float* st      = wt + 262144;
    float* lossbuf = st + 4096;
    const long nbuf = (long)Bc * C1_ * L_;
    float* A  = lossbuf + 64;
    float* Bb = A + nbuf;
    float* Cc = Bb + nbuf;

    const int D_ = C1_ / 2;

    // ---- one-time weight transposes (tiny) ----
    // normal conv:  so=CI*K si=K   sk=1  koff=0
    // tconv:        so=K    si=CO*K sk=-1 koff=K-1
    auto prep = [&](const float* w, long off, int CO, int cig, int K,
                    int so, int si, int sk, int koff) {
        int total = cig * K * CO;
        wprep_kernel<<<(total + 255) / 256, 256, 0, stream>>>(
            w, wt + off, CO, cig, K, so, si, sk, koff);
    };
    prep(W[0],  wo.w0,   C1_, ORG_, 7, ORG_ * 7, 7,        1,  0);   // w0
    prep(W[3],  wo.wxa,  D_,  C1_,  1, C1_,      1,        1,  0);   // wxa
    prep(W[6],  wo.wxb,  D_,  2,    5, 2 * 5,    5,        1,  0);   // wxb (grouped)
    prep(W[9],  wo.wxc,  C1_, D_,   1, D_,       1,        1,  0);   // wxc
    prep(W[12], wo.w2,   C2_, C1_,  3, C1_ * 3,  3,        1,  0);   // w2
    prep(W[16], wo.wd2,  C1_, C2_,  3, 3,        C1_ * 3, -1,  2);   // wd2 (tconv)
    prep(W[19], wo.wd1a, C1_, C1_,  5, 5,        C1_ * 5, -1,  4);   // wd1a (tconv)
    prep(W[22], wo.wd1b, C1_, C1_,  5, 5,        C1_ * 5, -1,  4);   // wd1b (tconv)
    prep(W[25], wo.wd0,  ORG_, C1_, 7, 7,        ORG_ * 7, -1, 6);   // wd0 (tconv)

    zero_kernel<<<1, 1, 0, stream>>>(lossbuf);

    for (int b0 = 0; b0 < B_; b0 += Bc) {
        const float* xc = x + (long)b0 * ORG_ * L_;
        float* outc = out + (long)b0 * ORG_ * L_;
        run_chunk(xc, W, wt, wo, outc, A, Bb, Cc, st, lossbuf, Bc, nbuf, stream);
    }

    // losses: commit_loss == vq_loss numerically
    {
        float invNP = 1.f / (float)(B_ * (L_ / 4));  // N = 65536
        finalize_kernel<<<1, 1, 0, stream>>>(lossbuf, out, invNP, (long)out_size - 2);
    }
}

// Round 4
// 3937.598 us; speedup vs baseline: 8.4705x; 1.4059x over previous
//
#include <hip/hip_runtime.h>
#include <math.h>

// ---------------- constants ----------------
static constexpr int B_   = 128;
static constexpr int ORG_ = 4;
static constexpr int L_   = 2048;
static constexpr int C1_  = 128;
static constexpr int C2_  = 64;
static constexpr int NG_  = 8;
static constexpr int VQD_ = 64;
static constexpr int VQN_ = 1024;

__device__ __forceinline__ float selu_f(float x) {
    const float scale = 1.0507009873554805f;
    const float alpha = 1.6732632423543772f;
    return scale * (x > 0.f ? x : alpha * expm1f(x));
}

// ---------------- weight prep: wT[(i*K + k)*CO + o] = w[o*so + i*si + k*sk + koff]
__global__ void wprep_kernel(const float* __restrict__ w, float* __restrict__ wT,
                             int CO, int cig, int K, int so, int si, int sk, int koff)
{
    int idx = blockIdx.x * 256 + threadIdx.x;
    int total = cig * K * CO;
    if (idx >= total) return;
    int o = idx % CO;
    int r = idx / CO;       // r = i*K + k
    int i = r / K, k = r % K;
    wT[idx] = w[(long)o * so + (long)i * si + (long)k * sk + koff];
}

// ---------------- LDS-tiled conv with optional fused input transform ----------------
// Input transform (if ist != null):  v = (raw - mu)*rsig*ig[c] + ibt[c]; [+ res]; [selu]
// Out-of-range t stays 0 (conv zero-padding of the *final* input tensor).
// thread: o = tid % CO, slot = tid / CO, NT = CO*TT/NTHR consecutive t outputs.
template<int K, int CO, int NTHR, int TT>
__global__ __launch_bounds__(NTHR) void conv_tile_kernel(
    const float* __restrict__ in, const float* __restrict__ wT,
    const float* __restrict__ scale, const float* __restrict__ bias,
    float* __restrict__ out,
    int CI, int T, int cig, int cog,
    const float* __restrict__ ist, const float* __restrict__ ig,
    const float* __restrict__ ibt, int icpg, int iselu,
    const float* __restrict__ res)
{
    constexpr int P    = (K - 1) / 2;
    constexpr int SPAN = TT + K - 1;
    constexpr int RS   = (SPAN + 3) & ~3;      // row stride, 16B aligned
    constexpr int NT   = (CO * TT) / NTHR;
    constexpr int XW   = NT + K - 1;
    extern __shared__ float lds[];

    const int tile = blockIdx.x;
    const int b    = blockIdx.y;
    const int t0g  = tile * TT;
    const float* inb = in + (long)b * CI * T;

    // stage padded (and transformed) input tile
    for (int idx = threadIdx.x; idx < CI * SPAN; idx += NTHR) {
        int c = idx / SPAN, j = idx % SPAN;
        int tt = t0g + j - P;
        float v = 0.f;
        if (tt >= 0 && tt < T) {
            v = inb[(long)c * T + tt];
            if (ist) {
                const float* s = &ist[2 * (b * NG_ + c / icpg)];
                v = (v - s[0]) * s[1] * ig[c] + ibt[c];
                if (res) v += res[((long)b * CI + c) * T + tt];
                if (iselu) v = selu_f(v);
            }
        }
        lds[c * RS + j] = v;
    }
    __syncthreads();

    const int o    = threadIdx.x % CO;
    const int slot = threadIdx.x / CO;
    const int t0   = slot * NT;
    const int g    = o / cog;
    const float* wrow = wT + o;

    float acc[NT];
#pragma unroll
    for (int u = 0; u < NT; ++u) acc[u] = 0.f;

    for (int i = 0; i < cig; ++i) {
        const int irow = g * cig + i;
        float xin[(XW + 3) & ~3];
        if constexpr (NT % 4 == 0) {
            constexpr int X4 = (XW + 3) / 4;
            const float4* l4 = reinterpret_cast<const float4*>(&lds[irow * RS + t0]);
#pragma unroll
            for (int j = 0; j < X4; ++j) {
                float4 v = l4[j];
                xin[4 * j]     = v.x;
                xin[4 * j + 1] = v.y;
                xin[4 * j + 2] = v.z;
                xin[4 * j + 3] = v.w;
            }
        } else {
#pragma unroll
            for (int j = 0; j < XW; ++j) xin[j] = lds[irow * RS + t0 + j];
        }
        float wk[K];
#pragma unroll
        for (int k = 0; k < K; ++k) wk[k] = wrow[(i * K + k) * CO];
#pragma unroll
        for (int u = 0; u < NT; ++u) {
#pragma unroll
            for (int k = 0; k < K; ++k) acc[u] = fmaf(xin[u + k], wk[k], acc[u]);
        }
    }

    const float sc = scale ? scale[o] : 1.f;
    const float bi = bias  ? bias[o]  : 0.f;
    float* ob = out + ((long)b * CO + o) * T + t0g + t0;
#pragma unroll
    for (int u = 0; u < NT; ++u) ob[u] = acc[u] * sc + bi;
}

// ---------------- GroupNorm stats: one block per (b,g), float4 reads ----------------
__global__ __launch_bounds__(256) void gn_stats_kernel(
    const float* __restrict__ x, float* __restrict__ stats,
    int C, int T, int G)
{
    const int bg = blockIdx.x;
    const int cpg = C / G;
    const int b = bg / G, g = bg % G;
    const float* base = x + ((long)b * C + (long)g * cpg) * T;
    const long n4 = (long)cpg * T / 4;
    const float4* b4 = (const float4*)base;
    float s = 0.f, ss = 0.f;
    for (long i = threadIdx.x; i < n4; i += blockDim.x) {
        float4 v = b4[i];
        s += v.x + v.y + v.z + v.w;
        ss += v.x * v.x + v.y * v.y + v.z * v.z + v.w * v.w;
    }
#pragma unroll
    for (int off = 32; off; off >>= 1) {
        s  += __shfl_down(s, off);
        ss += __shfl_down(ss, off);
    }
    __shared__ float sh_s[4], sh_ss[4];
    const int wid = threadIdx.x >> 6, lane = threadIdx.x & 63;
    if (lane == 0) { sh_s[wid] = s; sh_ss[wid] = ss; }
    __syncthreads();
    if (threadIdx.x == 0) {
        float S = 0.f, SS = 0.f;
        for (int i = 0; i < 4; ++i) { S += sh_s[i]; SS += sh_ss[i]; }
        float inv_n = 1.f / (float)((long)cpg * T);
        float mu  = S * inv_n;
        float var = SS * inv_n - mu * mu;
        stats[2 * bg]     = mu;
        stats[2 * bg + 1] = rsqrtf(var + 1e-5f);
    }
}

// ---------------- fused: out = maxpool2( selu( T1(x) + T2(r) ) ) ----------------
// T1: GN transform (no selu). T2: optional GN transform (+optional selu); if rst==null, r used raw.
__global__ __launch_bounds__(256) void pool_fused_kernel(
    const float* __restrict__ x, const float* __restrict__ xst,
    const float* __restrict__ xg, const float* __restrict__ xb, int xcpg,
    const float* __restrict__ r, const float* __restrict__ rst,
    const float* __restrict__ rg, const float* __restrict__ rb, int rcpg, int rselu,
    float* __restrict__ out, int C, int Tout, long total)
{
    for (long idx = blockIdx.x * (long)blockDim.x + threadIdx.x; idx < total;
         idx += (long)gridDim.x * blockDim.x) {
        const int to = (int)(idx % Tout);
        const int c  = (int)((idx / Tout) % C);
        const int b  = (int)(idx / ((long)Tout * C));
        const long base = ((long)b * C + c) * (2 * Tout);
        const float* sx = &xst[2 * (b * NG_ + c / xcpg)];
        const float xgc = sx[1] * xg[c], xbc = xb[c] - sx[0] * sx[1] * xg[c];
        float rgc = 1.f, rbc = 0.f;
        if (rst) {
            const float* sr = &rst[2 * (b * NG_ + c / rcpg)];
            rgc = sr[1] * rg[c]; rbc = rb[c] - sr[0] * sr[1] * rg[c];
        }
        float f[2];
#pragma unroll
        for (int q = 0; q < 2; ++q) {
            long t = base + 2 * to + q;
            float rv = r[t] * rgc + rbc;
            if (rst && rselu) rv = selu_f(rv);
            f[q] = selu_f(x[t] * xgc + xbc + rv);
        }
        out[((long)b * C + c) * Tout + to] = fmaxf(f[0], f[1]);
    }
}

// ---------------- fused: out = upsample2( selu( T(x) [+ res] ) ) ----------------
// one thread per INPUT element; res (if any) is already-final.
__global__ __launch_bounds__(256) void up_fused_kernel(
    const float* __restrict__ x, const float* __restrict__ xst,
    const float* __restrict__ xg, const float* __restrict__ xb, int xcpg,
    const float* __restrict__ res,
    float* __restrict__ out, int C, int Tin, long total)
{
    for (long idx = blockIdx.x * (long)blockDim.x + threadIdx.x; idx < total;
         idx += (long)gridDim.x * blockDim.x) {
        const int t = (int)(idx % Tin);
        const int c = (int)((idx / Tin) % C);
        const int b = (int)(idx / ((long)Tin * C));
        const float* s = &xst[2 * (b * NG_ + c / xcpg)];
        float v = (x[idx] - s[0]) * s[1] * xg[c] + xb[c];
        if (res) v += res[idx];
        v = selu_f(v);
        float2* o2 = (float2*)(out + (((long)b * C + c) * Tin + t) * 2);
        *o2 = make_float2(v, v);
    }
}

// ---------------- VQ ----------------
__global__ void wnorm_kernel(const float* __restrict__ codes, float* __restrict__ wn)
{
    int j = blockIdx.x * 256 + threadIdx.x;
    if (j >= VQN_) return;
    const float* c = codes + (long)j * VQD_;
    float s = 0.f;
#pragma unroll
    for (int i = 0; i < VQD_; ++i) s = fmaf(c[i], c[i], s);
    wn[j] = s;
}

// block = 256 threads: 64 points x 4 code-slices of 256. Wave lanes share code row (broadcast).
__global__ __launch_bounds__(256) void vq_kernel(
    const float* __restrict__ h, const float* __restrict__ codes,
    const float* __restrict__ wn, float* __restrict__ hq, float* __restrict__ loss,
    int T)
{
    const int p  = threadIdx.x & 63;
    const int cs = threadIdx.x >> 6;
    const int n  = blockIdx.x * 64 + p;
    const int b  = n / T, t = n % T;

    float z[VQD_];
#pragma unroll
    for (int c = 0; c < VQD_; ++c) z[c] = h[((long)b * VQD_ + c) * T + t];

    float best = 3.4e38f;
    int bj = 0;
    for (int j = cs * 256; j < cs * 256 + 256; ++j) {
        const float* cw = codes + (long)j * VQD_;
        float dot = 0.f;
#pragma unroll
        for (int c = 0; c < VQD_; ++c) dot = fmaf(z[c], cw[c], dot);
        float scv = wn[j] - 2.f * dot;
        if (scv < best) { best = scv; bj = j; }
    }

    __shared__ float sb[4][64];
    __shared__ int   sj[4][64];
    sb[cs][p] = best; sj[cs][p] = bj;
    __syncthreads();
    if (cs == 0) {
#pragma unroll
        for (int s = 1; s < 4; ++s)
            if (sb[s][p] < best) { best = sb[s][p]; bj = sj[s][p]; }
        const float* w = codes + (long)bj * VQD_;
        float l = 0.f;
#pragma unroll
        for (int c = 0; c < VQD_; ++c) {
            float wv = w[c];
            hq[((long)b * VQD_ + c) * T + t] = wv;
            float df = z[c] - wv;
            l = fmaf(df, df, l);
        }
#pragma unroll
        for (int off = 32; off; off >>= 1) l += __shfl_down(l, off);
        if (p == 0) atomicAdd(loss, l);
    }
}

__global__ void zero_kernel(float* p) { p[0] = 0.f; }

__global__ void finalize_kernel(const float* __restrict__ loss, float* __restrict__ out,
                                float invNP, long off)
{
    float v = loss[0] * invNP;
    out[off]     = v;
    out[off + 1] = v;
}

// ---------------- host side ----------------
static inline int nblk(long total, int thr = 256, long cap = 262144) {
    long b = (total + thr - 1) / thr;
    if (b > cap) b = cap;
    if (b < 1) b = 1;
    return (int)b;
}
static inline int ldsz(int CI, int K, int TT = 64) {
    int span = TT + K - 1;
    int rs = (span + 3) & ~3;
    return CI * rs * 4;
}

struct WT {
    long w0, wxa, wxb, wxc, w2, wd2, wd1a, wd1b, wd0, total;
};
static WT wt_offsets() {
    WT o; long p = 0;
    o.w0   = p; p += (long)ORG_ * 7 * C1_;
    o.wxa  = p; p += (long)C1_ * 1 * (C1_ / 2);
    o.wxb  = p; p += 2L * 5 * (C1_ / 2);
    o.wxc  = p; p += (long)(C1_ / 2) * 1 * C1_;
    o.w2   = p; p += (long)C1_ * 3 * C2_;
    o.wd2  = p; p += (long)C2_ * 3 * C1_;
    o.wd1a = p; p += (long)C1_ * 5 * C1_;
    o.wd1b = p; p += (long)C1_ * 5 * C1_;
    o.wd0  = p; p += (long)C1_ * 7 * ORG_;
    o.total = p;
    return o;
}

static void run_chunk(const float* x, const float* const* W, const float* wt,
                      const WT& wo, const float* wn, float* out,
                      float* A, float* Bb, float* Cc, float* st, float* lossbuf,
                      int Bc, long nbuf, hipStream_t stream)
{
    const float* g0_g  = W[1];
    const float* g0_b  = W[2];
    const float* gxa_g = W[4];
    const float* gxa_b = W[5];
    const float* gxb_g = W[7];
    const float* gxb_b = W[8];
    const float* gxc_g = W[10];
    const float* gxc_b = W[11];
    const float* bn2_g = W[13];
    const float* bn2_b = W[14];
    const float* embed = W[15];
    const float* gd2_g = W[17];
    const float* gd2_b = W[18];
    const float* gd1a_g= W[20];
    const float* gd1a_b= W[21];
    const float* gd1b_g= W[23];
    const float* gd1b_b= W[24];
    const float* bd0   = W[26];

    const int D_ = C1_ / 2;  // 64
    const int SLOT = 2048;   // floats per stats slot
    float* st0 = st + 0 * SLOT;   // g0
    float* st1 = st + 1 * SLOT;   // gxa / gd1a
    float* st2 = st + 2 * SLOT;   // gxb
    float* st3 = st + 3 * SLOT;   // gxc
    float* st4 = st + 4 * SLOT;   // gd2
    float* st5 = st + 5 * SLOT;   // gd1a (decoder)
    float* st6 = st + 6 * SLOT;   // gd1b

    int T = L_;  // 2048

    // ============ encoder ============
    // conv0: x -> A raw
    conv_tile_kernel<7, 128, 512, 64><<<dim3(T / 64, Bc), 512, ldsz(ORG_, 7), stream>>>(
        x, wt + wo.w0, nullptr, nullptr, A, ORG_, T, ORG_, C1_,
        nullptr, nullptr, nullptr, 0, 0, nullptr);
    gn_stats_kernel<<<Bc * NG_, 256, 0, stream>>>(A, st0, C1_, T, NG_);

    // ---- resx block 0 (input A raw, transform g0) ----
    conv_tile_kernel<1, 64, 512, 64><<<dim3(T / 64, Bc), 512, ldsz(C1_, 1), stream>>>(
        A, wt + wo.wxa, nullptr, nullptr, Bb, C1_, T, C1_, D_,
        st0, g0_g, g0_b, C1_ / NG_, 1, nullptr);
    gn_stats_kernel<<<Bc * NG_, 256, 0, stream>>>(Bb, st1, D_, T, NG_);

    conv_tile_kernel<5, 64, 512, 64><<<dim3(T / 64, Bc), 512, ldsz(D_, 5), stream>>>(
        Bb, wt + wo.wxb, nullptr, nullptr, Bb + nbuf / 2, D_, T, 2, 2,
        st1, gxa_g, gxa_b, D_ / NG_, 1, nullptr);
    gn_stats_kernel<<<Bc * NG_, 256, 0, stream>>>(Bb + nbuf / 2, st2, D_, T, NG_);

    conv_tile_kernel<1, 128, 512, 64><<<dim3(T / 64, Bc), 512, ldsz(D_, 1), stream>>>(
        Bb + nbuf / 2, wt + wo.wxc, nullptr, nullptr, Cc, D_, T, D_, C1_,
        st2, gxb_g, gxb_b, D_ / NG_, 1, nullptr);
    gn_stats_kernel<<<Bc * NG_, 256, 0, stream>>>(Cc, st3, C1_, T, NG_);

    // pool0: out = pool(selu(T_gxc(Cc) + selu(T_g0(A)))) -> Bb  (T 2048->1024)
    {
        int Tout = T / 2;
        long tt = (long)Bc * C1_ * Tout;
        pool_fused_kernel<<<nblk(tt), 256, 0, stream>>>(
            Cc, st3, gxc_g, gxc_b, C1_ / NG_,
            A, st0, g0_g, g0_b, C1_ / NG_, 1,
            Bb, C1_, Tout, tt);
        T = Tout;
    }

    // ---- resx block 1 (input Bb final) ----
    conv_tile_kernel<1, 64, 512, 64><<<dim3(T / 64, Bc), 512, ldsz(C1_, 1), stream>>>(
        Bb, wt + wo.wxa, nullptr, nullptr, Cc, C1_, T, C1_, D_,
        nullptr, nullptr, nullptr, 0, 0, nullptr);
    gn_stats_kernel<<<Bc * NG_, 256, 0, stream>>>(Cc, st1, D_, T, NG_);

    conv_tile_kernel<5, 64, 512, 64><<<dim3(T / 64, Bc), 512, ldsz(D_, 5), stream>>>(
        Cc, wt + wo.wxb, nullptr, nullptr, Cc + nbuf / 2, D_, T, 2, 2,
        st1, gxa_g, gxa_b, D_ / NG_, 1, nullptr);
    gn_stats_kernel<<<Bc * NG_, 256, 0, stream>>>(Cc + nbuf / 2, st2, D_, T, NG_);

    conv_tile_kernel<1, 128, 512, 64><<<dim3(T / 64, Bc), 512, ldsz(D_, 1), stream>>>(
        Cc + nbuf / 2, wt + wo.wxc, nullptr, nullptr, A, D_, T, D_, C1_,
        st2, gxb_g, gxb_b, D_ / NG_, 1, nullptr);
    gn_stats_kernel<<<Bc * NG_, 256, 0, stream>>>(A, st3, C1_, T, NG_);

    // pool1: out = pool(selu(T_gxc(A) + Bb)) -> Cc  (T 1024->512)
    {
        int Tout = T / 2;
        long tt = (long)Bc * C1_ * Tout;
        pool_fused_kernel<<<nblk(tt), 256, 0, stream>>>(
            A, st3, gxc_g, gxc_b, C1_ / NG_,
            Bb, nullptr, nullptr, nullptr, 0, 0,
            Cc, C1_, Tout, tt);
        T = Tout;
    }

    // res2: conv k3 128->64 + BN affine epilogue -> Bb
    conv_tile_kernel<3, 64, 512, 64><<<dim3(T / 64, Bc), 512, ldsz(C1_, 3), stream>>>(
        Cc, wt + wo.w2, bn2_g, bn2_b, Bb, C1_, T, C1_, C2_,
        nullptr, nullptr, nullptr, 0, 0, nullptr);

    // ============ VQ ============  (Bb -> hq in A)
    {
        int NP = Bc * T;
        vq_kernel<<<NP / 64, 256, 0, stream>>>(Bb, embed, wn, A, lossbuf, T);
    }

    // ============ decoder ============
    // deres2: tconv(A) -> Bb raw
    conv_tile_kernel<3, 128, 512, 64><<<dim3(T / 64, Bc), 512, ldsz(C2_, 3), stream>>>(
        A, wt + wo.wd2, nullptr, nullptr, Bb, C2_, T, C2_, C1_,
        nullptr, nullptr, nullptr, 0, 0, nullptr);
    gn_stats_kernel<<<Bc * NG_, 256, 0, stream>>>(Bb, st4, C1_, T, NG_);

    // up0: Cc = up(selu(T_gd2(Bb)))  (512 -> 1024)
    {
        long tt = (long)Bc * C1_ * T;
        up_fused_kernel<<<nblk(tt), 256, 0, stream>>>(
            Bb, st4, gd2_g, gd2_b, C1_ / NG_, nullptr, Cc, C1_, T, tt);
        T *= 2;
    }

    // stage 0 deres1 at T=1024
    conv_tile_kernel<5, 128, 512, 64><<<dim3(T / 64, Bc), 512, ldsz(C1_, 5), stream>>>(
        Cc, wt + wo.wd1a, nullptr, nullptr, A, C1_, T, C1_, C1_,
        nullptr, nullptr, nullptr, 0, 0, nullptr);
    gn_stats_kernel<<<Bc * NG_, 256, 0, stream>>>(A, st5, C1_, T, NG_);

    conv_tile_kernel<5, 128, 512, 64><<<dim3(T / 64, Bc), 512, ldsz(C1_, 5), stream>>>(
        A, wt + wo.wd1b, nullptr, nullptr, Bb, C1_, T, C1_, C1_,
        st5, gd1a_g, gd1a_b, C1_ / NG_, 1, nullptr);
    gn_stats_kernel<<<Bc * NG_, 256, 0, stream>>>(Bb, st6, C1_, T, NG_);

    // up1: A = up(selu(T_gd1b(Bb) + Cc))  (1024 -> 2048)
    {
        long tt = (long)Bc * C1_ * T;
        up_fused_kernel<<<nblk(tt), 256, 0, stream>>>(
            Bb, st6, gd1b_g, gd1b_b, C1_ / NG_, Cc, A, C1_, T, tt);
        T *= 2;
    }

    // stage 1 deres1 at T=2048
    conv_tile_kernel<5, 128, 512, 64><<<dim3(T / 64, Bc), 512, ldsz(C1_, 5), stream>>>(
        A, wt + wo.wd1a, nullptr, nullptr, Cc, C1_, T, C1_, C1_,
        nullptr, nullptr, nullptr, 0, 0, nullptr);
    gn_stats_kernel<<<Bc * NG_, 256, 0, stream>>>(Cc, st5, C1_, T, NG_);

    conv_tile_kernel<5, 128, 512, 64><<<dim3(T / 64, Bc), 512, ldsz(C1_, 5), stream>>>(
        Cc, wt + wo.wd1b, nullptr, nullptr, Bb, C1_, T, C1_, C1_,
        st5, gd1a_g, gd1a_b, C1_ / NG_, 1, nullptr);
    gn_stats_kernel<<<Bc * NG_, 256, 0, stream>>>(Bb, st6, C1_, T, NG_);

    // deres0: tconv(selu(T_gd1b(Bb) + A)) + bd0 -> out
    conv_tile_kernel<7, 4, 256, 64><<<dim3(T / 64, Bc), 256, ldsz(C1_, 7), stream>>>(
        Bb, wt + wo.wd0, nullptr, bd0, out, C1_, T, C1_, ORG_,
        st6, gd1b_g, gd1b_b, C1_ / NG_, 1, A);
}

extern "C" void kernel_launch(void* const* d_in, const int* in_sizes, int n_in,
                              void* d_out, int out_size, void* d_ws, size_t ws_size,
                              hipStream_t stream) {
    const float* x = (const float*)d_in[0];
    const float* W[27];
    for (int i = 0; i < 27; ++i) W[i] = (const float*)d_in[i + 1];

    float* out = (float*)d_out;
    const WT wo = wt_offsets();

    // workspace: [wT pool | wnorm | stats(8 slots) | loss | A | B | C]
    const long FIXED = 262144 + 1024 + 8 * 2048 + 64;
    int Bc = 0;
    for (int cand = B_; cand >= 1; cand >>= 1) {
        size_t need = ((size_t)FIXED + (size_t)3 * cand * C1_ * L_) * sizeof(float);
        if (need <= ws_size) { Bc = cand; break; }
    }
    if (Bc == 0) return;

    float* wt      = (float*)d_ws;
    float* wn      = wt + 262144;
    float* st      = wn + 1024;
    float* lossbuf = st + 8 * 2048;
    const long nbuf = (long)Bc * C1_ * L_;
    float* A  = lossbuf + 64;
    float* Bb = A + nbuf;
    float* Cc = Bb + nbuf;

    const int D_ = C1_ / 2;

    // one-time weight transposes + code norms
    auto prep = [&](const float* w, long off, int CO, int cig, int K,
                    int so, int si, int sk, int koff) {
        int total = cig * K * CO;
        wprep_kernel<<<(total + 255) / 256, 256, 0, stream>>>(
            w, wt + off, CO, cig, K, so, si, sk, koff);
    };
    prep(W[0],  wo.w0,   C1_, ORG_, 7, ORG_ * 7, 7,        1,  0);
    prep(W[3],  wo.wxa,  D_,  C1_,  1, C1_,      1,        1,  0);
    prep(W[6],  wo.wxb,  D_,  2,    5, 2 * 5,    5,        1,  0);
    prep(W[9],  wo.wxc,  C1_, D_,   1, D_,       1,        1,  0);
    prep(W[12], wo.w2,   C2_, C1_,  3, C1_ * 3,  3,        1,  0);
    prep(W[16], wo.wd2,  C1_, C2_,  3, 3,        C1_ * 3, -1,  2);
    prep(W[19], wo.wd1a, C1_, C1_,  5, 5,        C1_ * 5, -1,  4);
    prep(W[22], wo.wd1b, C1_, C1_,  5, 5,        C1_ * 5, -1,  4);
    prep(W[25], wo.wd0,  ORG_, C1_, 7, 7,        ORG_ * 7, -1, 6);
    wnorm_kernel<<<(VQN_ + 255) / 256, 256, 0, stream>>>(W[15], wn);

    zero_kernel<<<1, 1, 0, stream>>>(lossbuf);

    for (int b0 = 0; b0 < B_; b0 += Bc) {
        const float* xc = x + (long)b0 * ORG_ * L_;
        float* outc = out + (long)b0 * ORG_ * L_;
        run_chunk(xc, W, wt, wo, wn, outc, A, Bb, Cc, st, lossbuf, Bc, nbuf, stream);
    }

    {
        float invNP = 1.f / (float)(B_ * (L_ / 4));  // N = 65536
        finalize_kernel<<<1, 1, 0, stream>>>(lossbuf, out, invNP, (long)out_size - 2);
    }
}

// Round 5
// 2595.840 us; speedup vs baseline: 12.8487x; 1.5169x over previous
//
#include <hip/hip_runtime.h>
#include <math.h>

// ---------------- constants ----------------
static constexpr int B_   = 128;
static constexpr int ORG_ = 4;
static constexpr int L_   = 2048;
static constexpr int C1_  = 128;
static constexpr int C2_  = 64;
static constexpr int NG_  = 8;
static constexpr int VQD_ = 64;
static constexpr int VQN_ = 1024;

typedef __attribute__((ext_vector_type(8))) short bf16x8;
typedef __attribute__((ext_vector_type(4))) float f32x4;

__device__ __forceinline__ float selu_f(float x) {
    const float scale = 1.0507009873554805f;
    const float alpha = 1.6732632423543772f;
    return scale * (x > 0.f ? x : alpha * expm1f(x));
}
__device__ __forceinline__ unsigned short f2bf(float x) {
    unsigned u = __float_as_uint(x);
    u = (u + 0x7FFFu + ((u >> 16) & 1u)) >> 16;
    return (unsigned short)u;
}

// ---------------- weight prep (f32 direct-conv layout) ----------------
__global__ void wprep_kernel(const float* __restrict__ w, float* __restrict__ wT,
                             int CO, int cig, int K, int so, int si, int sk, int koff)
{
    int idx = blockIdx.x * 256 + threadIdx.x;
    int total = cig * K * CO;
    if (idx >= total) return;
    int o = idx % CO;
    int r = idx / CO;
    int i = r / K, k = r % K;
    wT[idx] = w[(long)o * so + (long)i * si + (long)k * sk + koff];
}

// ---------------- weight prep (MFMA bf16 layout) for tconv 128x128 K=5 ----------------
// wb[((k*16 + ic*4 + ig)*128 + o)*8 + j] = bf16( w[i][o][4-k] ), i = ic*32 + ig*8 + j
__global__ void wprep_mfma_kernel(const float* __restrict__ w, unsigned short* __restrict__ wb)
{
    int idx = blockIdx.x * 256 + threadIdx.x;   // total 81920
    if (idx >= 5 * 16 * 128 * 8) return;
    int j  = idx & 7;
    int o  = (idx >> 3) & 127;
    int kk = idx >> 10;          // 0..79
    int ig = kk & 3, ic = (kk >> 2) & 3, k = kk >> 4;
    int i  = ic * 32 + ig * 8 + j;
    wb[idx] = f2bf(w[(long)i * (128 * 5) + o * 5 + (4 - k)]);
}

// ---------------- LDS-tiled f32 conv with optional fused input transform ----------------
template<int K, int CO, int NTHR, int TT>
__global__ __launch_bounds__(NTHR) void conv_tile_kernel(
    const float* __restrict__ in, const float* __restrict__ wT,
    const float* __restrict__ scale, const float* __restrict__ bias,
    float* __restrict__ out,
    int CI, int T, int cig, int cog,
    const float* __restrict__ ist, const float* __restrict__ ig,
    const float* __restrict__ ibt, int icpg, int iselu,
    const float* __restrict__ res)
{
    constexpr int P    = (K - 1) / 2;
    constexpr int SPAN = TT + K - 1;
    constexpr int RS   = (SPAN + 3) & ~3;
    constexpr int NT   = (CO * TT) / NTHR;
    constexpr int XW   = NT + K - 1;
    extern __shared__ float lds[];

    const int tile = blockIdx.x;
    const int b    = blockIdx.y;
    const int t0g  = tile * TT;
    const float* inb = in + (long)b * CI * T;

    for (int idx = threadIdx.x; idx < CI * SPAN; idx += NTHR) {
        int c = idx / SPAN, j = idx % SPAN;
        int tt = t0g + j - P;
        float v = 0.f;
        if (tt >= 0 && tt < T) {
            v = inb[(long)c * T + tt];
            if (ist) {
                const float* s = &ist[2 * (b * NG_ + c / icpg)];
                v = (v - s[0]) * s[1] * ig[c] + ibt[c];
                if (res) v += res[((long)b * CI + c) * T + tt];
                if (iselu) v = selu_f(v);
            }
        }
        lds[c * RS + j] = v;
    }
    __syncthreads();

    const int o    = threadIdx.x % CO;
    const int slot = threadIdx.x / CO;
    const int t0   = slot * NT;
    const int g    = o / cog;
    const float* wrow = wT + o;

    float acc[NT];
#pragma unroll
    for (int u = 0; u < NT; ++u) acc[u] = 0.f;

    for (int i = 0; i < cig; ++i) {
        const int irow = g * cig + i;
        float xin[(XW + 3) & ~3];
        if constexpr (NT % 4 == 0) {
            constexpr int X4 = (XW + 3) / 4;
            const float4* l4 = reinterpret_cast<const float4*>(&lds[irow * RS + t0]);
#pragma unroll
            for (int j = 0; j < X4; ++j) {
                float4 v = l4[j];
                xin[4 * j]     = v.x;
                xin[4 * j + 1] = v.y;
                xin[4 * j + 2] = v.z;
                xin[4 * j + 3] = v.w;
            }
        } else {
#pragma unroll
            for (int j = 0; j < XW; ++j) xin[j] = lds[irow * RS + t0 + j];
        }
        float wk[K];
#pragma unroll
        for (int k = 0; k < K; ++k) wk[k] = wrow[(i * K + k) * CO];
#pragma unroll
        for (int u = 0; u < NT; ++u) {
#pragma unroll
            for (int k = 0; k < K; ++k) acc[u] = fmaf(xin[u + k], wk[k], acc[u]);
        }
    }

    const float sc = scale ? scale[o] : 1.f;
    const float bi = bias  ? bias[o]  : 0.f;
    float* ob = out + ((long)b * CO + o) * T + t0g + t0;
#pragma unroll
    for (int u = 0; u < NT; ++u) ob[u] = acc[u] * sc + bi;
}

// ---------------- MFMA bf16 conv: CI=128, CO=128, K=5 (decoder deres1) ----------------
// Block: 256 thr (4 waves), tile 128o x 64t. X staged transposed [t][i] bf16 in LDS.
// Weight layout from wprep_mfma. Optional fused GN+selu on input staging.
__global__ __launch_bounds__(256) void conv_mfma5_kernel(
    const float* __restrict__ in, const unsigned short* __restrict__ wb,
    float* __restrict__ out, int T,
    const float* __restrict__ ist, const float* __restrict__ ig_,
    const float* __restrict__ ibt, int icpg)
{
    constexpr int SPAN = 68, RSI = 136;
    __shared__ unsigned short xlds[SPAN * RSI];   // 18.5 KB

    const int t0g = blockIdx.x * 64;
    const int b   = blockIdx.y;
    const float* inb = in + (long)b * 128 * T;

    for (int idx = threadIdx.x; idx < 128 * SPAN; idx += 256) {
        int i = idx / SPAN, j = idx % SPAN;
        int tt = t0g + j - 2;
        float v = 0.f;
        if (tt >= 0 && tt < T) {
            v = inb[(long)i * T + tt];
            if (ist) {
                const float* s = &ist[2 * (b * NG_ + i / icpg)];
                v = selu_f((v - s[0]) * s[1] * ig_[i] + ibt[i]);
            }
        }
        xlds[j * RSI + i] = f2bf(v);
    }
    __syncthreads();

    const int lane = threadIdx.x & 63;
    const int wid  = threadIdx.x >> 6;
    const int tw   = wid * 16;        // wave's 16-t slice
    const int mr   = lane & 15;
    const int kg   = lane >> 4;

    f32x4 acc[8];
#pragma unroll
    for (int ot = 0; ot < 8; ++ot) acc[ot] = (f32x4){0.f, 0.f, 0.f, 0.f};

#pragma unroll
    for (int k = 0; k < 5; ++k) {
#pragma unroll
        for (int ic = 0; ic < 4; ++ic) {
            bf16x8 a = *(const bf16x8*)&xlds[(tw + mr + k) * RSI + ic * 32 + kg * 8];
            const unsigned short* wp = wb + (((k * 16 + ic * 4 + kg) * 128) + mr) * 8;
#pragma unroll
            for (int ot = 0; ot < 8; ++ot) {
                bf16x8 bfr = *(const bf16x8*)(wp + ot * 16 * 8);
                acc[ot] = __builtin_amdgcn_mfma_f32_16x16x32_bf16(a, bfr, acc[ot], 0, 0, 0);
            }
        }
    }

#pragma unroll
    for (int ot = 0; ot < 8; ++ot) {
        int o = ot * 16 + mr;
        float4 v = make_float4(acc[ot][0], acc[ot][1], acc[ot][2], acc[ot][3]);
        *(float4*)&out[((long)b * 128 + o) * T + t0g + tw + kg * 4] = v;
    }
}

// ---------------- GroupNorm stats ----------------
__global__ __launch_bounds__(256) void gn_stats_kernel(
    const float* __restrict__ x, float* __restrict__ stats,
    int C, int T, int G)
{
    const int bg = blockIdx.x;
    const int cpg = C / G;
    const int b = bg / G, g = bg % G;
    const float* base = x + ((long)b * C + (long)g * cpg) * T;
    const long n4 = (long)cpg * T / 4;
    const float4* b4 = (const float4*)base;
    float s = 0.f, ss = 0.f;
    for (long i = threadIdx.x; i < n4; i += blockDim.x) {
        float4 v = b4[i];
        s += v.x + v.y + v.z + v.w;
        ss += v.x * v.x + v.y * v.y + v.z * v.z + v.w * v.w;
    }
#pragma unroll
    for (int off = 32; off; off >>= 1) {
        s  += __shfl_down(s, off);
        ss += __shfl_down(ss, off);
    }
    __shared__ float sh_s[4], sh_ss[4];
    const int wid = threadIdx.x >> 6, lane = threadIdx.x & 63;
    if (lane == 0) { sh_s[wid] = s; sh_ss[wid] = ss; }
    __syncthreads();
    if (threadIdx.x == 0) {
        float S = 0.f, SS = 0.f;
        for (int i = 0; i < 4; ++i) { S += sh_s[i]; SS += sh_ss[i]; }
        float inv_n = 1.f / (float)((long)cpg * T);
        float mu  = S * inv_n;
        float var = SS * inv_n - mu * mu;
        stats[2 * bg]     = mu;
        stats[2 * bg + 1] = rsqrtf(var + 1e-5f);
    }
}

// ---------------- fused: out = maxpool2( selu( T1(x) + T2(r) ) ) ----------------
__global__ __launch_bounds__(256) void pool_fused_kernel(
    const float* __restrict__ x, const float* __restrict__ xst,
    const float* __restrict__ xg, const float* __restrict__ xb, int xcpg,
    const float* __restrict__ r, const float* __restrict__ rst,
    const float* __restrict__ rg, const float* __restrict__ rb, int rcpg, int rselu,
    float* __restrict__ out, int C, int Tout, long total)
{
    for (long idx = blockIdx.x * (long)blockDim.x + threadIdx.x; idx < total;
         idx += (long)gridDim.x * blockDim.x) {
        const int to = (int)(idx % Tout);
        const int c  = (int)((idx / Tout) % C);
        const int b  = (int)(idx / ((long)Tout * C));
        const long base = ((long)b * C + c) * (2 * Tout);
        const float* sx = &xst[2 * (b * NG_ + c / xcpg)];
        const float xgc = sx[1] * xg[c], xbc = xb[c] - sx[0] * sx[1] * xg[c];
        float rgc = 1.f, rbc = 0.f;
        if (rst) {
            const float* sr = &rst[2 * (b * NG_ + c / rcpg)];
            rgc = sr[1] * rg[c]; rbc = rb[c] - sr[0] * sr[1] * rg[c];
        }
        float f[2];
#pragma unroll
        for (int q = 0; q < 2; ++q) {
            long t = base + 2 * to + q;
            float rv = r[t] * rgc + rbc;
            if (rst && rselu) rv = selu_f(rv);
            f[q] = selu_f(x[t] * xgc + xbc + rv);
        }
        out[((long)b * C + c) * Tout + to] = fmaxf(f[0], f[1]);
    }
}

// ---------------- fused: out = upsample2( selu( T(x) [+ res] ) ) ----------------
__global__ __launch_bounds__(256) void up_fused_kernel(
    const float* __restrict__ x, const float* __restrict__ xst,
    const float* __restrict__ xg, const float* __restrict__ xb, int xcpg,
    const float* __restrict__ res,
    float* __restrict__ out, int C, int Tin, long total)
{
    for (long idx = blockIdx.x * (long)blockDim.x + threadIdx.x; idx < total;
         idx += (long)gridDim.x * blockDim.x) {
        const int t = (int)(idx % Tin);
        const int c = (int)((idx / Tin) % C);
        const int b = (int)(idx / ((long)Tin * C));
        const float* s = &xst[2 * (b * NG_ + c / xcpg)];
        float v = (x[idx] - s[0]) * s[1] * xg[c] + xb[c];
        if (res) v += res[idx];
        v = selu_f(v);
        float2* o2 = (float2*)(out + (((long)b * C + c) * Tin + t) * 2);
        *o2 = make_float2(v, v);
    }
}

// ---------------- VQ ----------------
__global__ void wnorm_kernel(const float* __restrict__ codes, float* __restrict__ wn)
{
    int j = blockIdx.x * 256 + threadIdx.x;
    if (j >= VQN_) return;
    const float* c = codes + (long)j * VQD_;
    float s = 0.f;
#pragma unroll
    for (int i = 0; i < VQD_; ++i) s = fmaf(c[i], c[i], s);
    wn[j] = s;
}

// block = 256 thr: 32 points x 8 code-slices of 128.  Scan order & tie-breaking
// identical to previous version (ascending j, strict <; slices combined ascending).
__global__ __launch_bounds__(256) void vq_kernel(
    const float* __restrict__ h, const float* __restrict__ codes,
    const float* __restrict__ wn, float* __restrict__ hq, float* __restrict__ loss,
    int T)
{
    const int p  = threadIdx.x & 31;
    const int cs = threadIdx.x >> 5;
    const int n  = blockIdx.x * 32 + p;
    const int b  = n / T, t = n % T;

    float z[VQD_];
#pragma unroll
    for (int c = 0; c < VQD_; ++c) z[c] = h[((long)b * VQD_ + c) * T + t];

    float best = 3.4e38f;
    int bj = cs * 128;
    for (int j = cs * 128; j < cs * 128 + 128; ++j) {
        const float4* cw4 = (const float4*)(codes + (long)j * VQD_);
        float dot = 0.f;
#pragma unroll
        for (int q = 0; q < VQD_ / 4; ++q) {
            float4 w4 = cw4[q];
            dot = fmaf(z[4 * q],     w4.x, dot);
            dot = fmaf(z[4 * q + 1], w4.y, dot);
            dot = fmaf(z[4 * q + 2], w4.z, dot);
            dot = fmaf(z[4 * q + 3], w4.w, dot);
        }
        float scv = wn[j] - 2.f * dot;
        if (scv < best) { best = scv; bj = j; }
    }

    __shared__ float sb[8][32];
    __shared__ int   sj[8][32];
    __shared__ int   sjb[32];
    sb[cs][p] = best; sj[cs][p] = bj;
    __syncthreads();
    if (cs == 0) {
#pragma unroll
        for (int s = 1; s < 8; ++s)
            if (sb[s][p] < best) { best = sb[s][p]; bj = sj[s][p]; }
        sjb[p] = bj;
    }
    __syncthreads();

    const int bjp = sjb[p];
    const float* wj = codes + (long)bjp * VQD_;
    float l = 0.f;
#pragma unroll
    for (int cc = 0; cc < 8; ++cc) {
        int c = cs * 8 + cc;
        float wv = wj[c];
        hq[((long)b * VQD_ + c) * T + t] = wv;
        float df = z[c] - wv;
        l = fmaf(df, df, l);
    }
#pragma unroll
    for (int off = 32; off; off >>= 1) l += __shfl_down(l, off);
    if ((threadIdx.x & 63) == 0) atomicAdd(loss, l);
}

__global__ void zero_kernel(float* p) { p[0] = 0.f; }

__global__ void finalize_kernel(const float* __restrict__ loss, float* __restrict__ out,
                                float invNP, long off)
{
    float v = loss[0] * invNP;
    out[off]     = v;
    out[off + 1] = v;
}

// ---------------- host side ----------------
static inline int nblk(long total, int thr = 256, long cap = 262144) {
    long b = (total + thr - 1) / thr;
    if (b > cap) b = cap;
    if (b < 1) b = 1;
    return (int)b;
}
static inline int ldsz(int CI, int K, int TT = 64) {
    int span = TT + K - 1;
    int rs = (span + 3) & ~3;
    return CI * rs * 4;
}

struct WT {
    long w0, wxa, wxb, wxc, w2, wd2, wd0, total;
};
static WT wt_offsets() {
    WT o; long p = 0;
    o.w0   = p; p += (long)ORG_ * 7 * C1_;
    o.wxa  = p; p += (long)C1_ * 1 * (C1_ / 2);
    o.wxb  = p; p += 2L * 5 * (C1_ / 2);
    o.wxc  = p; p += (long)(C1_ / 2) * 1 * C1_;
    o.w2   = p; p += (long)C1_ * 3 * C2_;
    o.wd2  = p; p += (long)C2_ * 3 * C1_;
    o.wd0  = p; p += (long)C1_ * 7 * ORG_;
    o.total = p;
    return o;
}

static void run_chunk(const float* x, const float* const* W, const float* wt,
                      const WT& wo, const unsigned short* wbA, const unsigned short* wbB,
                      const float* wn, float* out,
                      float* A, float* Bb, float* Cc, float* st, float* lossbuf,
                      int Bc, long nbuf, hipStream_t stream)
{
    const float* g0_g  = W[1];
    const float* g0_b  = W[2];
    const float* gxa_g = W[4];
    const float* gxa_b = W[5];
    const float* gxb_g = W[7];
    const float* gxb_b = W[8];
    const float* gxc_g = W[10];
    const float* gxc_b = W[11];
    const float* bn2_g = W[13];
    const float* bn2_b = W[14];
    const float* embed = W[15];
    const float* gd2_g = W[17];
    const float* gd2_b = W[18];
    const float* gd1a_g= W[20];
    const float* gd1a_b= W[21];
    const float* gd1b_g= W[23];
    const float* gd1b_b= W[24];
    const float* bd0   = W[26];

    const int D_ = C1_ / 2;  // 64
    const int SLOT = 2048;
    float* st0 = st + 0 * SLOT;
    float* st1 = st + 1 * SLOT;
    float* st2 = st + 2 * SLOT;
    float* st3 = st + 3 * SLOT;
    float* st4 = st + 4 * SLOT;
    float* st5 = st + 5 * SLOT;
    float* st6 = st + 6 * SLOT;

    int T = L_;  // 2048

    // ============ encoder (all f32; must stay bit-stable for VQ argmin) ============
    conv_tile_kernel<7, 128, 512, 64><<<dim3(T / 64, Bc), 512, ldsz(ORG_, 7), stream>>>(
        x, wt + wo.w0, nullptr, nullptr, A, ORG_, T, ORG_, C1_,
        nullptr, nullptr, nullptr, 0, 0, nullptr);
    gn_stats_kernel<<<Bc * NG_, 256, 0, stream>>>(A, st0, C1_, T, NG_);

    conv_tile_kernel<1, 64, 512, 64><<<dim3(T / 64, Bc), 512, ldsz(C1_, 1), stream>>>(
        A, wt + wo.wxa, nullptr, nullptr, Bb, C1_, T, C1_, D_,
        st0, g0_g, g0_b, C1_ / NG_, 1, nullptr);
    gn_stats_kernel<<<Bc * NG_, 256, 0, stream>>>(Bb, st1, D_, T, NG_);

    conv_tile_kernel<5, 64, 512, 64><<<dim3(T / 64, Bc), 512, ldsz(D_, 5), stream>>>(
        Bb, wt + wo.wxb, nullptr, nullptr, Bb + nbuf / 2, D_, T, 2, 2,
        st1, gxa_g, gxa_b, D_ / NG_, 1, nullptr);
    gn_stats_kernel<<<Bc * NG_, 256, 0, stream>>>(Bb + nbuf / 2, st2, D_, T, NG_);

    conv_tile_kernel<1, 128, 512, 64><<<dim3(T / 64, Bc), 512, ldsz(D_, 1), stream>>>(
        Bb + nbuf / 2, wt + wo.wxc, nullptr, nullptr, Cc, D_, T, D_, C1_,
        st2, gxb_g, gxb_b, D_ / NG_, 1, nullptr);
    gn_stats_kernel<<<Bc * NG_, 256, 0, stream>>>(Cc, st3, C1_, T, NG_);

    {
        int Tout = T / 2;
        long tt = (long)Bc * C1_ * Tout;
        pool_fused_kernel<<<nblk(tt), 256, 0, stream>>>(
            Cc, st3, gxc_g, gxc_b, C1_ / NG_,
            A, st0, g0_g, g0_b, C1_ / NG_, 1,
            Bb, C1_, Tout, tt);
        T = Tout;
    }

    conv_tile_kernel<1, 64, 512, 64><<<dim3(T / 64, Bc), 512, ldsz(C1_, 1), stream>>>(
        Bb, wt + wo.wxa, nullptr, nullptr, Cc, C1_, T, C1_, D_,
        nullptr, nullptr, nullptr, 0, 0, nullptr);
    gn_stats_kernel<<<Bc * NG_, 256, 0, stream>>>(Cc, st1, D_, T, NG_);

    conv_tile_kernel<5, 64, 512, 64><<<dim3(T / 64, Bc), 512, ldsz(D_, 5), stream>>>(
        Cc, wt + wo.wxb, nullptr, nullptr, Cc + nbuf / 2, D_, T, 2, 2,
        st1, gxa_g, gxa_b, D_ / NG_, 1, nullptr);
    gn_stats_kernel<<<Bc * NG_, 256, 0, stream>>>(Cc + nbuf / 2, st2, D_, T, NG_);

    conv_tile_kernel<1, 128, 512, 64><<<dim3(T / 64, Bc), 512, ldsz(D_, 1), stream>>>(
        Cc + nbuf / 2, wt + wo.wxc, nullptr, nullptr, A, D_, T, D_, C1_,
        st2, gxb_g, gxb_b, D_ / NG_, 1, nullptr);
    gn_stats_kernel<<<Bc * NG_, 256, 0, stream>>>(A, st3, C1_, T, NG_);

    {
        int Tout = T / 2;
        long tt = (long)Bc * C1_ * Tout;
        pool_fused_kernel<<<nblk(tt), 256, 0, stream>>>(
            A, st3, gxc_g, gxc_b, C1_ / NG_,
            Bb, nullptr, nullptr, nullptr, 0, 0,
            Cc, C1_, Tout, tt);
        T = Tout;
    }

    conv_tile_kernel<3, 64, 512, 64><<<dim3(T / 64, Bc), 512, ldsz(C1_, 3), stream>>>(
        Cc, wt + wo.w2, bn2_g, bn2_b, Bb, C1_, T, C1_, C2_,
        nullptr, nullptr, nullptr, 0, 0, nullptr);

    // ============ VQ ============  (Bb -> hq in A)
    {
        int NP = Bc * T;
        vq_kernel<<<NP / 32, 256, 0, stream>>>(Bb, embed, wn, A, lossbuf, T);
    }

    // ============ decoder ============
    conv_tile_kernel<3, 128, 512, 64><<<dim3(T / 64, Bc), 512, ldsz(C2_, 3), stream>>>(
        A, wt + wo.wd2, nullptr, nullptr, Bb, C2_, T, C2_, C1_,
        nullptr, nullptr, nullptr, 0, 0, nullptr);
    gn_stats_kernel<<<Bc * NG_, 256, 0, stream>>>(Bb, st4, C1_, T, NG_);

    {
        long tt = (long)Bc * C1_ * T;
        up_fused_kernel<<<nblk(tt), 256, 0, stream>>>(
            Bb, st4, gd2_g, gd2_b, C1_ / NG_, nullptr, Cc, C1_, T, tt);
        T *= 2;
    }

    // stage 0 deres1 at T=1024 (MFMA bf16)
    conv_mfma5_kernel<<<dim3(T / 64, Bc), 256, 0, stream>>>(
        Cc, wbA, A, T, nullptr, nullptr, nullptr, 0);
    gn_stats_kernel<<<Bc * NG_, 256, 0, stream>>>(A, st5, C1_, T, NG_);

    conv_mfma5_kernel<<<dim3(T / 64, Bc), 256, 0, stream>>>(
        A, wbB, Bb, T, st5, gd1a_g, gd1a_b, C1_ / NG_);
    gn_stats_kernel<<<Bc * NG_, 256, 0, stream>>>(Bb, st6, C1_, T, NG_);

    {
        long tt = (long)Bc * C1_ * T;
        up_fused_kernel<<<nblk(tt), 256, 0, stream>>>(
            Bb, st6, gd1b_g, gd1b_b, C1_ / NG_, Cc, A, C1_, T, tt);
        T *= 2;
    }

    // stage 1 deres1 at T=2048 (MFMA bf16)
    conv_mfma5_kernel<<<dim3(T / 64, Bc), 256, 0, stream>>>(
        A, wbA, Cc, T, nullptr, nullptr, nullptr, 0);
    gn_stats_kernel<<<Bc * NG_, 256, 0, stream>>>(Cc, st5, C1_, T, NG_);

    conv_mfma5_kernel<<<dim3(T / 64, Bc), 256, 0, stream>>>(
        Cc, wbB, Bb, T, st5, gd1a_g, gd1a_b, C1_ / NG_);
    gn_stats_kernel<<<Bc * NG_, 256, 0, stream>>>(Bb, st6, C1_, T, NG_);

    // deres0: tconv(selu(T_gd1b(Bb) + A)) + bd0 -> out  (f32, K=7, CO=4)
    conv_tile_kernel<7, 4, 256, 64><<<dim3(T / 64, Bc), 256, ldsz(C1_, 7), stream>>>(
        Bb, wt + wo.wd0, nullptr, bd0, out, C1_, T, C1_, ORG_,
        st6, gd1b_g, gd1b_b, C1_ / NG_, 1, A);
}

extern "C" void kernel_launch(void* const* d_in, const int* in_sizes, int n_in,
                              void* d_out, int out_size, void* d_ws, size_t ws_size,
                              hipStream_t stream) {
    const float* x = (const float*)d_in[0];
    const float* W[27];
    for (int i = 0; i < 27; ++i) W[i] = (const float*)d_in[i + 1];

    float* out = (float*)d_out;
    const WT wo = wt_offsets();

    // workspace: [wT f32 pool | bf16 MFMA weights (2x81920 u16) | wnorm | stats | loss | A | B | C]
    const long WT_F32   = 262144;                 // f32 slots for wT pool (generous)
    const long WB_F32   = 2 * 81920 / 2;          // 81920 f32-equiv for two bf16 weight packs
    const long FIXED = WT_F32 + WB_F32 + 1024 + 8 * 2048 + 64;
    int Bc = 0;
    for (int cand = B_; cand >= 1; cand >>= 1) {
        size_t need = ((size_t)FIXED + (size_t)3 * cand * C1_ * L_) * sizeof(float);
        if (need <= ws_size) { Bc = cand; break; }
    }
    if (Bc == 0) return;

    float* wt            = (float*)d_ws;
    unsigned short* wbA  = (unsigned short*)(wt + WT_F32);
    unsigned short* wbB  = wbA + 81920;
    float* wn            = wt + WT_F32 + WB_F32;
    float* st            = wn + 1024;
    float* lossbuf       = st + 8 * 2048;
    const long nbuf = (long)Bc * C1_ * L_;
    float* A  = lossbuf + 64;
    float* Bb = A + nbuf;
    float* Cc = Bb + nbuf;

    const int D_ = C1_ / 2;

    auto prep = [&](const float* w, long off, int CO, int cig, int K,
                    int so, int si, int sk, int koff) {
        int total = cig * K * CO;
        wprep_kernel<<<(total + 255) / 256, 256, 0, stream>>>(
            w, wt + off, CO, cig, K, so, si, sk, koff);
    };
    prep(W[0],  wo.w0,   C1_, ORG_, 7, ORG_ * 7, 7,        1,  0);
    prep(W[3],  wo.wxa,  D_,  C1_,  1, C1_,      1,        1,  0);
    prep(W[6],  wo.wxb,  D_,  2,    5, 2 * 5,    5,        1,  0);
    prep(W[9],  wo.wxc,  C1_, D_,   1, D_,       1,        1,  0);
    prep(W[12], wo.w2,   C2_, C1_,  3, C1_ * 3,  3,        1,  0);
    prep(W[16], wo.wd2,  C1_, C2_,  3, 3,        C1_ * 3, -1,  2);
    prep(W[25], wo.wd0,  ORG_, C1_, 7, 7,        ORG_ * 7, -1, 6);
    wprep_mfma_kernel<<<81920 / 256, 256, 0, stream>>>(W[19], wbA);  // wd1a
    wprep_mfma_kernel<<<81920 / 256, 256, 0, stream>>>(W[22], wbB);  // wd1b
    wnorm_kernel<<<(VQN_ + 255) / 256, 256, 0, stream>>>(W[15], wn);

    zero_kernel<<<1, 1, 0, stream>>>(lossbuf);

    for (int b0 = 0; b0 < B_; b0 += Bc) {
        const float* xc = x + (long)b0 * ORG_ * L_;
        float* outc = out + (long)b0 * ORG_ * L_;
        run_chunk(xc, W, wt, wo, wbA, wbB, wn, outc, A, Bb, Cc, st, lossbuf, Bc, nbuf, stream);
    }

    {
        float invNP = 1.f / (float)(B_ * (L_ / 4));  // N = 65536
        finalize_kernel<<<1, 1, 0, stream>>>(lossbuf, out, invNP, (long)out_size - 2);
    }
}